// Round 2
// baseline (1321.355 us; speedup 1.0000x reference)
//
#include <hip/hip_runtime.h>
#include <hip/hip_bf16.h>

typedef __bf16 v8bf __attribute__((ext_vector_type(8)));
typedef __bf16 v4bf __attribute__((ext_vector_type(4)));
typedef float  v4f  __attribute__((ext_vector_type(4)));

#define NMEM 262144
#define CFD  256       // per-feature dim (indiv / collab halves)
#define NSEA 8192

// ---------------- workspace layout (bytes) ----------------
// T1  = Wo@Wv            f32 [512][512]   @ 0          (1048576)
// W3  = Wfc@T1           f32 [256][512]   @ 1048576    (524288)
// bc  = Wo@bv + bo       f32 [512]        @ 1572864    (2048)
// b3  = Wfc@bc + bfc     f32 [256]        @ 1574912    (1024)
// Bp  = W3 packed bf16 MFMA B-frags       @ 1575936    (262144)
// sums   f32 [8192]                       @ 1838080    (32768)
// counts f32 [8192]                       @ 1870848    (32768)

// ---------------- precompute kernels ----------------

__global__ __launch_bounds__(256)
void gemm_nn(const float* __restrict__ A, const float* __restrict__ B,
             float* __restrict__ C, int M, int Nn, int K) {
  __shared__ float As[16][68];   // [k][m] (A-tile transposed), +4 pad
  __shared__ float Bs[16][68];   // [k][n]
  const int tid = threadIdx.x;
  const int tx = tid & 15, ty = tid >> 4;
  const int row0 = blockIdx.y * 64, col0 = blockIdx.x * 64;
  const int lr = tid >> 2, lk = (tid & 3) << 2;     // A-load: row, k4
  const int br = tid >> 4, bc = (tid & 15) << 2;    // B-load: k-row, col4
  float acc[4][4] = {};
  for (int kk = 0; kk < K; kk += 16) {
    const float4 a4 = *(const float4*)(A + (size_t)(row0 + lr) * K + kk + lk);
    const float4 b4 = *(const float4*)(B + (size_t)(kk + br) * Nn + col0 + bc);
    __syncthreads();               // protect previous iteration's readers
    As[lk + 0][lr] = a4.x; As[lk + 1][lr] = a4.y;
    As[lk + 2][lr] = a4.z; As[lk + 3][lr] = a4.w;
    *(float4*)&Bs[br][bc] = b4;
    __syncthreads();
#pragma unroll
    for (int t = 0; t < 16; ++t) {
      const float4 av = *(const float4*)&As[t][ty << 2];
      const float4 bv = *(const float4*)&Bs[t][tx << 2];
      acc[0][0] += av.x * bv.x; acc[0][1] += av.x * bv.y;
      acc[0][2] += av.x * bv.z; acc[0][3] += av.x * bv.w;
      acc[1][0] += av.y * bv.x; acc[1][1] += av.y * bv.y;
      acc[1][2] += av.y * bv.z; acc[1][3] += av.y * bv.w;
      acc[2][0] += av.z * bv.x; acc[2][1] += av.z * bv.y;
      acc[2][2] += av.z * bv.z; acc[2][3] += av.z * bv.w;
      acc[3][0] += av.w * bv.x; acc[3][1] += av.w * bv.y;
      acc[3][2] += av.w * bv.z; acc[3][3] += av.w * bv.w;
    }
  }
#pragma unroll
  for (int i = 0; i < 4; ++i) {
    const float4 o = make_float4(acc[i][0], acc[i][1], acc[i][2], acc[i][3]);
    *(float4*)(C + (size_t)(row0 + (ty << 2) + i) * Nn + col0 + (tx << 2)) = o;
  }
}

__global__ void bias_dot(const float* __restrict__ W, const float* __restrict__ x,
                         const float* __restrict__ b, float* __restrict__ o, int K) {
  const int i = blockIdx.x, L = threadIdx.x;  // 64 threads/block
  const float* row = W + (size_t)i * K;
  float s = 0.f;
  for (int k = L; k < K; k += 64) s += row[k] * x[k];
#pragma unroll
  for (int m = 32; m; m >>= 1) s += __shfl_xor(s, m, 64);
  if (L == 0) o[i] = s + b[i];
}

// Pack W3[256][512] (row-major f32) into bf16 MFMA B fragments:
// Bp[nt][kc][lane][j] = W3[nt*16 + (lane&15)][kc*32 + (lane>>4)*8 + j]
__global__ void pack_b(const float* __restrict__ W3, __bf16* __restrict__ Bp) {
  const int t = blockIdx.x * 256 + threadIdx.x;   // 16384 threads total
  const int L = t & 63, kc = (t >> 6) & 15, nt = t >> 10;
  const int n = nt * 16 + (L & 15);
  const int k = kc * 32 + ((L >> 4) << 3);
  const float* src = W3 + n * 512 + k;
  __bf16* dst = Bp + (size_t)t * 8;
#pragma unroll
  for (int j = 0; j < 8; ++j) dst[j] = (__bf16)src[j];
}

// ---------------- fused main kernel ----------------
// Block: 256 threads (4 waves), 64 members/block (16 per wave).
// LDS 32 KiB; occupancy intentionally register-limited at ~3 blocks/CU
// (round-1 showed forcing 4-5 blocks via reg squeeze is a net loss).
//
// Phase A (restructured, 2-pass): lanes {4i..4i+3} own member i.
//   pass 1: each lane accumulates 4 partial dots over its 64-col quarter
//           (80 independent b128 loads -> deep MLP), 2-step shfl reduce,
//           alpha softmax computed ONCE for all 16 members in parallel
//           (was: 16 serial iterations x 6-step wave-wide reduce).
//   pass 2: re-read S/R/H (L1/L2-hot), write bf16 agg fragments to LDS
//           in swizzled MFMA layout us = u ^ ((u>>4)&7) (bijective,
//           matches phase-B reader; writes at b128 bank floor).
// Phase C: B tile register-prefetched one tile ahead (async-stage split)
//           so the ~250cy L2 latency hides under MFMA; acc chain split 2x.

__global__ __launch_bounds__(256, 3)
void fused_main(const float* __restrict__ indiv,
                const float* __restrict__ hier,
                const float* __restrict__ stren,
                const float* __restrict__ rec,
                const int*   __restrict__ sid,
                const float* __restrict__ w1,
                const __bf16* __restrict__ Bp,
                const float* __restrict__ b3,
                const float* __restrict__ wout,
                float* __restrict__ sums,
                float* __restrict__ counts) {
  __shared__ __align__(16) char smem[32768];

  const int tid = threadIdx.x;
  const int w = tid >> 6, L = tid & 63;
  const int mbase = blockIdx.x * 64 + w * 16;
  __bf16* const xw = (__bf16*)(smem + (w << 13));   // this wave's 8 KiB frag store

  // ---- phase A: pass 1 — partial dots with deep MLP ----
  const int i4  = L >> 2;        // member within wave's 16
  const int sub = L & 3;         // which 64-col quarter this lane covers
  const float* hrow = hier  + (size_t)(mbase + i4) * CFD + sub * 64;
  const float* srow = stren + (size_t)(mbase + i4) * CFD + sub * 64;
  const float* rrow = rec   + (size_t)(mbase + i4) * CFD + sub * 64;
  const float* wa = w1 + sub * 64;         // weights for H (first 256)
  const float* wb = w1 + 256 + sub * 64;   // weights for S/R/H (last 256)

  float4 aHa = {0.f,0.f,0.f,0.f}, aSb = {0.f,0.f,0.f,0.f};
  float4 aRb = {0.f,0.f,0.f,0.f}, aHb = {0.f,0.f,0.f,0.f};
#pragma unroll 4
  for (int t = 0; t < 16; ++t) {
    const float4 h = *(const float4*)(hrow + 4 * t);
    const float4 s = *(const float4*)(srow + 4 * t);
    const float4 r = *(const float4*)(rrow + 4 * t);
    const float4 a = *(const float4*)(wa + 4 * t);
    const float4 b = *(const float4*)(wb + 4 * t);
    aHa.x += a.x*h.x; aHa.y += a.y*h.y; aHa.z += a.z*h.z; aHa.w += a.w*h.w;
    aSb.x += b.x*s.x; aSb.y += b.y*s.y; aSb.z += b.z*s.z; aSb.w += b.w*s.w;
    aRb.x += b.x*r.x; aRb.y += b.y*r.y; aRb.z += b.z*r.z; aRb.w += b.w*r.w;
    aHb.x += b.x*h.x; aHb.y += b.y*h.y; aHb.z += b.z*h.z; aHb.w += b.w*h.w;
  }
  float pHa = (aHa.x + aHa.y) + (aHa.z + aHa.w);
  float pSb = (aSb.x + aSb.y) + (aSb.z + aSb.w);
  float pRb = (aRb.x + aRb.y) + (aRb.z + aRb.w);
  float pHb = (aHb.x + aHb.y) + (aHb.z + aHb.w);
#pragma unroll
  for (int m = 1; m <= 2; m <<= 1) {
    pHa += __shfl_xor(pHa, m, 64);
    pSb += __shfl_xor(pSb, m, 64);
    pRb += __shfl_xor(pRb, m, 64);
    pHb += __shfl_xor(pHb, m, 64);
  }
  const float q1 = pHa + pSb;   // e(H,S) pre-act
  const float q2 = pHa + pRb;   // e(H,R)
  const float q3 = pHa + pHb;   // e(H,H)
  const float e1 = q1 > 0.f ? q1 : 0.01f * q1;
  const float e2 = q2 > 0.f ? q2 : 0.01f * q2;
  const float e3 = q3 > 0.f ? q3 : 0.01f * q3;
  const float mx = fmaxf(e1, fmaxf(e2, e3));
  float a1 = __expf(e1 - mx), a2 = __expf(e2 - mx), a3 = __expf(e3 - mx);
  const float inv = 1.f / (a1 + a2 + a3);
  a1 *= inv; a2 *= inv; a3 *= inv;

  // ---- phase A: pass 2 — agg -> swizzled fragment LDS (re-reads are L1/L2-hot)
#pragma unroll
  for (int j = 0; j < 8; ++j) {
    const float4 s0 = *(const float4*)(srow + 8 * j);
    const float4 s1 = *(const float4*)(srow + 8 * j + 4);
    const float4 r0 = *(const float4*)(rrow + 8 * j);
    const float4 r1 = *(const float4*)(rrow + 8 * j + 4);
    const float4 h0 = *(const float4*)(hrow + 8 * j);
    const float4 h1 = *(const float4*)(hrow + 8 * j + 4);
    v8bf g;
    g[0] = (__bf16)(a1 * s0.x + a2 * r0.x + a3 * h0.x);
    g[1] = (__bf16)(a1 * s0.y + a2 * r0.y + a3 * h0.y);
    g[2] = (__bf16)(a1 * s0.z + a2 * r0.z + a3 * h0.z);
    g[3] = (__bf16)(a1 * s0.w + a2 * r0.w + a3 * h0.w);
    g[4] = (__bf16)(a1 * s1.x + a2 * r1.x + a3 * h1.x);
    g[5] = (__bf16)(a1 * s1.y + a2 * r1.y + a3 * h1.y);
    g[6] = (__bf16)(a1 * s1.z + a2 * r1.z + a3 * h1.z);
    g[7] = (__bf16)(a1 * s1.w + a2 * r1.w + a3 * h1.w);
    // cols sub*64 + 8j .. +7 of member i4:
    // unit u = (c<<6)|(q<<4)|i4 with c = sub*2 + (j>>2), q = j&3
    const int c = sub * 2 + (j >> 2);
    const int u = (c << 6) | ((j & 3) << 4) | i4;
    const int us = u ^ ((u >> 4) & 7);
    *(v8bf*)(xw + us * 8) = g;
  }

  // ---- phase B: A fragments in registers ----
  // lane holds A[m = L&15][k = (L>>4)*8 + j] per 32-wide K chunk
  const int ml = L & 15;
  const int qo = (L >> 4) * 8;
  v8bf af[16];
  {
    const float* ip = indiv + (size_t)(mbase + ml) * CFD;
#pragma unroll
    for (int cc = 0; cc < 8; ++cc) {
      const float4 f0 = *(const float4*)(ip + cc * 32 + qo);
      const float4 f1 = *(const float4*)(ip + cc * 32 + qo + 4);
      v8bf t;
      t[0] = (__bf16)f0.x; t[1] = (__bf16)f0.y; t[2] = (__bf16)f0.z; t[3] = (__bf16)f0.w;
      t[4] = (__bf16)f1.x; t[5] = (__bf16)f1.y; t[6] = (__bf16)f1.z; t[7] = (__bf16)f1.w;
      af[cc] = t;
    }
#pragma unroll
    for (int cc = 0; cc < 8; ++cc) {
      const int u  = (cc << 6) | L;
      const int us = u ^ ((u >> 4) & 7);
      af[8 + cc] = *(const v8bf*)(xw + us * 8);
    }
  }

  // ---- phase C: 16 output tiles of 16; B tile prefetched one ahead ----
  float p0 = 0.f, p1 = 0.f, p2 = 0.f, p3 = 0.f;
  const uint4* bsrc = (const uint4*)Bp;
  uint4* bl = (uint4*)smem;
  const v8bf* btile = (const v8bf*)smem;
  uint4 breg0 = bsrc[tid];
  uint4 breg1 = bsrc[tid + 256];
  uint4 breg2 = bsrc[tid + 512];
  uint4 breg3 = bsrc[tid + 768];
  for (int nt = 0; nt < 16; ++nt) {
    __syncthreads();                       // fences phase-B readers / prev tile
    bl[tid      ] = breg0;
    bl[tid + 256] = breg1;
    bl[tid + 512] = breg2;
    bl[tid + 768] = breg3;
    if (nt < 15) {                         // prefetch next tile (hides L2 latency)
      const uint4* nb = bsrc + (nt + 1) * 1024 + tid;
      breg0 = nb[0]; breg1 = nb[256]; breg2 = nb[512]; breg3 = nb[768];
    }
    __syncthreads();

    v4f acc0 = {0.f, 0.f, 0.f, 0.f};
    v4f acc1 = {0.f, 0.f, 0.f, 0.f};
#pragma unroll
    for (int c = 0; c < 16; c += 2) {
      acc0 = __builtin_amdgcn_mfma_f32_16x16x32_bf16(af[c],     btile[c * 64 + L],       acc0, 0, 0, 0);
      acc1 = __builtin_amdgcn_mfma_f32_16x16x32_bf16(af[c + 1], btile[(c + 1) * 64 + L], acc1, 0, 0, 0);
    }
    const float b3n = b3[nt * 16 + ml];
    const float wn  = wout[nt * 16 + ml];
    p0 += fmaxf(acc0[0] + acc1[0] + b3n, 0.f) * wn;
    p1 += fmaxf(acc0[1] + acc1[1] + b3n, 0.f) * wn;
    p2 += fmaxf(acc0[2] + acc1[2] + b3n, 0.f) * wn;
    p3 += fmaxf(acc0[3] + acc1[3] + b3n, 0.f) * wn;
  }

  // reduce across the 16 lanes (same L>>4 group) holding different n columns
#pragma unroll
  for (int m = 8; m; m >>= 1) {
    p0 += __shfl_xor(p0, m, 64);
    p1 += __shfl_xor(p1, m, 64);
    p2 += __shfl_xor(p2, m, 64);
    p3 += __shfl_xor(p3, m, 64);
  }
  // C row m = (L>>4)*4 + r ; writer lanes: r = L&15 in [0,4)
  const int r = ml;
  if (r < 4) {
    const float pv = (r == 0) ? p0 : (r == 1) ? p1 : (r == 2) ? p2 : p3;
    const int mem = mbase + (L >> 4) * 4 + r;
    const int s = sid[mem];
    atomicAdd(&sums[s], pv);
    atomicAdd(&counts[s], 1.0f);
  }
}

__global__ void finalize_k(const float* __restrict__ sums,
                           const float* __restrict__ counts,
                           const float* __restrict__ bout,
                           float* __restrict__ out) {
  const int s = blockIdx.x * 256 + threadIdx.x;
  if (s < NSEA) out[s] = sums[s] / fmaxf(counts[s], 1.0f) + bout[0];
}

// ---------------- launch ----------------

extern "C" void kernel_launch(void* const* d_in, const int* in_sizes, int n_in,
                              void* d_out, int out_size, void* d_ws, size_t ws_size,
                              hipStream_t stream) {
  (void)in_sizes; (void)n_in; (void)out_size; (void)ws_size;
  const float* indiv = (const float*)d_in[0];
  const float* hier  = (const float*)d_in[1];
  const float* stren = (const float*)d_in[2];
  const float* rec   = (const float*)d_in[3];
  const int*   sid   = (const int*)d_in[4];
  const float* w1    = (const float*)d_in[5];
  // d_in[6..9]: Wq,bq,Wk,bk — dead code (softmax over size-1 axis == 1)
  const float* Wv    = (const float*)d_in[10];
  const float* bv    = (const float*)d_in[11];
  const float* Wo    = (const float*)d_in[12];
  const float* bo    = (const float*)d_in[13];
  const float* Wfc   = (const float*)d_in[14];
  const float* bfc   = (const float*)d_in[15];
  const float* wout  = (const float*)d_in[16];
  const float* bout  = (const float*)d_in[17];
  float* out = (float*)d_out;

  char* ws = (char*)d_ws;
  float*  T1   = (float*)(ws + 0);
  float*  W3   = (float*)(ws + 1048576);
  float*  bc   = (float*)(ws + 1572864);
  float*  b3   = (float*)(ws + 1574912);
  __bf16* Bp   = (__bf16*)(ws + 1575936);
  float*  sums = (float*)(ws + 1838080);
  float*  cnts = (float*)(ws + 1870848);

  hipMemsetAsync(ws + 1838080, 0, 65536, stream);   // sums + counts

  gemm_nn<<<dim3(8, 8), 256, 0, stream>>>(Wo,  Wv, T1, 512, 512, 512);
  bias_dot<<<512, 64, 0, stream>>>(Wo, bv, bo, bc, 512);
  gemm_nn<<<dim3(8, 4), 256, 0, stream>>>(Wfc, T1, W3, 256, 512, 512);
  bias_dot<<<256, 64, 0, stream>>>(Wfc, bc, bfc, b3, 512);
  pack_b<<<64, 256, 0, stream>>>(W3, Bp);

  fused_main<<<NMEM / 64, 256, 0, stream>>>(indiv, hier, stren, rec, sid, w1,
                                            Bp, b3, wout, sums, cnts);
  finalize_k<<<NSEA / 256, 256, 0, stream>>>(sums, cnts, bout, out);
}